// Round 2
// baseline (403.858 us; speedup 1.0000x reference)
//
#include <hip/hip_runtime.h>

#define BB 16
#define HW 4096
#define DIMC 256
#define NHEAD 8
#define CPH 8
#define NQKV 192
#define SCALE 0.17677669529663687f

typedef __attribute__((ext_vector_type(8))) short bf16x8;
typedef __attribute__((ext_vector_type(4))) float f32x4;

__device__ inline unsigned short f2b(float f) {
  union { float f; unsigned int u; } x; x.f = f;
  unsigned int r = x.u + 0x7FFFu + ((x.u >> 16) & 1u);
  return (unsigned short)(r >> 16);
}
__device__ inline float b2f(unsigned short u) {
  union { unsigned int u; float f; } x; x.u = ((unsigned int)u) << 16;
  return x.f;
}
__device__ inline void async_copy16(const void* g, void* l) {
  __builtin_amdgcn_global_load_lds((const __attribute__((address_space(1))) void*)g,
                                   (__attribute__((address_space(3))) void*)l, 16, 0, 0);
}

// ---------------- K0a: x (B,256k,4096s) fp32 -> xT (B,4096s,256k) bf16 ----------------
__global__ __launch_bounds__(256) void cast_xT(const float* __restrict__ x,
                                               unsigned short* __restrict__ xT) {
  __shared__ float Xs[64][69];
  const int b = blockIdx.z;
  const int k0 = blockIdx.y * 64;
  const int s0 = blockIdx.x * 64;
  const int tid = threadIdx.x;
  const float* xb = x + (size_t)b * (DIMC * HW);
#pragma unroll
  for (int i = 0; i < 4; ++i) {
    int idx = tid + i * 256;
    int kr = idx >> 4, f = idx & 15;
    float4 v = *(const float4*)&xb[(size_t)(k0 + kr) * HW + s0 + f * 4];
    Xs[kr][f * 4 + 0] = v.x; Xs[kr][f * 4 + 1] = v.y;
    Xs[kr][f * 4 + 2] = v.z; Xs[kr][f * 4 + 3] = v.w;
  }
  __syncthreads();
  unsigned short* ob = xT + (size_t)b * (HW * DIMC);
#pragma unroll
  for (int i = 0; i < 2; ++i) {
    int slot = tid + i * 256;
    int sr = slot >> 3, g8 = slot & 7;
    unsigned short pk[8];
#pragma unroll
    for (int j = 0; j < 8; ++j) pk[j] = f2b(Xs[g8 * 8 + j][sr]);
    *(uint4*)&ob[(size_t)(s0 + sr) * DIMC + k0 + g8 * 8] = *(uint4*)pk;
  }
}

// ---------------- K0b: qkv_w -> bf16 A-fragment-swizzled ; block 24 builds prep ----------------
// prep layout (floats): [0,864)   Afp[c][p][12] : (I + w1)[c][p][rs], 16B-aligned rows
//                       [864,960) Vb[c][12]     : dcb + dc1b
//                       [960,1056) Rb[n][12]    : rpb
__global__ __launch_bounds__(256) void cast_qw(const float* __restrict__ qw,
                                               unsigned short* __restrict__ qwf,
                                               const float* __restrict__ dcb,
                                               const float* __restrict__ w1,
                                               const float* __restrict__ dc1b,
                                               const float* __restrict__ rpb,
                                               float* __restrict__ prep) {
  if (blockIdx.x == 24) {
    for (int e = threadIdx.x; e < 1056; e += 256) {
      float v = 0.f;
      if (e < 864) {
        int cp = e / 12, rs = e - cp * 12;           // cp = c*9+p
        if (rs < 9) v = w1[cp * 9 + rs] + ((cp % 9) == rs ? 1.f : 0.f);
      } else if (e < 960) {
        int i = e - 864; int c = i / 12, p = i - c * 12;
        if (p < 9) v = dcb[c * 9 + p] + dc1b[c * 9 + p];
      } else {
        int i = e - 960; int n = i / 12, p = i - n * 12;
        if (p < 9) v = rpb[n * 9 + p];
      }
      prep[e] = v;
    }
    return;
  }
  int t = blockIdx.x * 256 + threadIdx.x;  // 6144
  int lane = t & 63;
  int cell = t >> 6;  // band*8 + c32
  int m = lane & 15, g = lane >> 4;
  int band = cell >> 3, c32 = cell & 7;
  int j = band * 16 + m;
  int k = c32 * 32 + g * 8;
  unsigned short pk[8];
#pragma unroll
  for (int i = 0; i < 8; ++i) pk[i] = f2b(qw[j * 256 + k + i]);
  *(uint4*)&qwf[(size_t)t * 8] = *(uint4*)pk;
}

// ---------------- K0c: proj_w (256,64) -> bf16 A-fragment-swizzled ----------------
__global__ __launch_bounds__(256) void cast_pw(const float* __restrict__ pw,
                                               unsigned short* __restrict__ pwf) {
  int t = blockIdx.x * 256 + threadIdx.x;  // 2048
  int lane = t & 63;
  int cell = t >> 6;  // band*2 + c32
  int m = lane & 15, g = lane >> 4;
  int band = cell >> 1, c32 = cell & 1;
  int d = band * 16 + m;
  int j = c32 * 32 + g * 8;
  unsigned short pk[8];
#pragma unroll
  for (int i = 0; i < 8; ++i) pk[i] = f2b(pw[d * 64 + j + i]);
  *(uint4*)&pwf[(size_t)t * 8] = *(uint4*)pk;
}

// ---------------- K1: qkv GEMM via bf16 MFMA ----------------
__global__ __launch_bounds__(256) void qkv_mfma(const unsigned short* __restrict__ xT,
                                                const unsigned short* __restrict__ qwf,
                                                const float* __restrict__ qb,
                                                unsigned short* __restrict__ qkvt) {
  __shared__ unsigned short Bs[128 * 256];
  const int b = blockIdx.y;
  const int s_blk = blockIdx.x * 128;
  const int tid = threadIdx.x;
  const int wave = tid >> 6, lane = tid & 63;

  {
    const int row_in = lane >> 5, cst = lane & 31;
#pragma unroll
    for (int ii = 0; ii < 16; ++ii) {
      int i = wave * 16 + ii;
      int s_row = 2 * i + row_in;
      int mem_chunk = (cst & 24) | ((cst ^ s_row) & 7);
      const unsigned short* src =
          xT + ((size_t)b * HW + s_blk + s_row) * DIMC + mem_chunk * 8;
      async_copy16(src, (char*)Bs + i * 1024);
    }
  }
  __syncthreads();

  f32x4 acc[3][8];
#pragma unroll
  for (int t = 0; t < 3; ++t)
#pragma unroll
    for (int st = 0; st < 8; ++st) acc[t][st] = (f32x4){0.f, 0.f, 0.f, 0.f};

  const int n = lane & 15, g = lane >> 4;
#pragma unroll
  for (int c32 = 0; c32 < 8; ++c32) {
    bf16x8 af[3];
#pragma unroll
    for (int t = 0; t < 3; ++t) {
      int band = wave * 3 + t;
      af[t] = *(const bf16x8*)(qwf + ((size_t)(band * 8 + c32) * 64 + lane) * 8);
    }
#pragma unroll
    for (int st = 0; st < 8; ++st) {
      int s_row = st * 16 + n;
      int mc = c32 * 4 + g;
      int stc = (mc & 24) | ((mc ^ s_row) & 7);
      bf16x8 bf = *(const bf16x8*)&Bs[s_row * 256 + stc * 8];
#pragma unroll
      for (int t = 0; t < 3; ++t)
        acc[t][st] = __builtin_amdgcn_mfma_f32_16x16x32_bf16(af[t], bf, acc[t][st], 0, 0, 0);
    }
  }

  unsigned short* ob = qkvt + (size_t)b * (NQKV * HW);
#pragma unroll
  for (int t = 0; t < 3; ++t) {
    int j0 = (wave * 3 + t) * 16 + g * 4;
#pragma unroll
    for (int st = 0; st < 8; ++st) {
      int s = s_blk + st * 16 + n;
#pragma unroll
      for (int r = 0; r < 4; ++r) {
        float v = acc[t][st][r] + qb[j0 + r];
        ob[(size_t)(j0 + r) * HW + s] = f2b(v);
      }
    }
  }
}

// ---------------- K2 v4: fused attn ----------------
// (a) plog -> single [9][128] accumulated via LDS atomicAdd (ds_add_f32):
// -32KB LDS, -1 barrier, no reduce phase. (b) A/Vb/Rb loaded from precomputed `prep`
// as wave-uniform L2-broadcast dwordx4; identity pre-baked; Af register-resident under
// __launch_bounds__(512,4) (128 VGPR cap) instead of rematerialized from LDS at 64 VGPR.
// (c) halos stored as float2 (row y, row y+4): 18 conflict-free ds_read_b64 replace 36 b32.
__global__ __launch_bounds__(512, 4) void attn_kernel(const unsigned short* __restrict__ qkvt,
                                                      const float* __restrict__ prep,
                                                      unsigned short* __restrict__ aoT) {
  __shared__ float2 hal2[16][6][20];   // kk(0-7)/vv(8-15); [y][x] pairs (y, y+4). 15360 B
  __shared__ float plog[9][128];       // summed logits, atomically accumulated. 4608 B
  __shared__ unsigned short ot[128][8];// transpose buffer for aoT write. 2048 B

  const int bn = blockIdx.x;   // b*8+n
  const int tile = blockIdx.y; // 0..31 : 8 y-tiles x 4 x-tiles
  const int b = bn >> 3, n = bn & 7;
  const int h0 = (tile >> 2) * 8, w0 = (tile & 3) * 16;
  const int tid = threadIdx.x;
  const int c = tid >> 6, lane = tid & 63;
  const int ly = lane >> 4, lx = lane & 15;
  const int s0 = (h0 + ly) * 64 + (w0 + lx);
  const int s1 = s0 + 256;  // +4 rows
  const unsigned short* fb = qkvt + ((size_t)b * NQKV + n * 24) * HW;

  // zero logit accumulator
  for (int e = tid; e < 1152; e += 512) ((float*)plog)[e] = 0.f;

  // stage halos: 16 bufs x 10 rows x 18 cols -> float2 rows (y, y+4)
  for (int e = tid; e < 2880; e += 512) {
    int cb = e / 180;
    int rem = e - cb * 180;
    int y = rem / 18, xx = rem - y * 18;
    int gy = h0 - 1 + y, gx = w0 - 1 + xx;
    float v = 0.f;
    if ((unsigned)gy < 64u && (unsigned)gx < 64u)
      v = b2f(fb[(size_t)(8 + cb) * HW + gy * 64 + gx]);
    if (y < 6) hal2[cb][y][xx].x = v;
    if (y >= 4) hal2[cb][y - 4][xx].y = v;
  }

  // wave-uniform broadcast loads of A (identity baked), K-base, V-base
  float Af[81];
  {
    const float* ap = prep + c * 108;
#pragma unroll
    for (int p = 0; p < 9; ++p) {
      float4 a0 = *(const float4*)(ap + p * 12);
      float4 a1 = *(const float4*)(ap + p * 12 + 4);
      Af[p * 9 + 0] = a0.x; Af[p * 9 + 1] = a0.y; Af[p * 9 + 2] = a0.z; Af[p * 9 + 3] = a0.w;
      Af[p * 9 + 4] = a1.x; Af[p * 9 + 5] = a1.y; Af[p * 9 + 6] = a1.z; Af[p * 9 + 7] = a1.w;
      Af[p * 9 + 8] = ap[p * 12 + 8];
    }
  }
  float Kb[9], Vb[9];
  {
    const float* vp = prep + 864 + c * 12;
    const float* rp = prep + 960 + n * 12;
#pragma unroll
    for (int p = 0; p < 9; ++p) { float d = vp[p]; Vb[p] = d; Kb[p] = d + rp[p]; }
  }

  float qc0 = SCALE * b2f(fb[(size_t)c * HW + s0]);
  float qc1 = SCALE * b2f(fb[(size_t)c * HW + s1]);
  __syncthreads();

  // ---- K phase (both pixels), accumulate q*k into plog via LDS float atomics ----
  {
    float2 t[9];
#pragma unroll
    for (int dy = 0; dy < 3; ++dy)
#pragma unroll
      for (int dx = 0; dx < 3; ++dx)
        t[dy * 3 + dx] = hal2[c][ly + dy][lx + dx];
#pragma unroll
    for (int p = 0; p < 9; ++p) {
      float kx = Kb[p], ky = Kb[p];
#pragma unroll
      for (int rs = 0; rs < 9; ++rs) {
        kx = fmaf(Af[p * 9 + rs], t[rs].x, kx);
        ky = fmaf(Af[p * 9 + rs], t[rs].y, ky);
      }
      atomicAdd(&plog[p][lane], qc0 * kx);
      atomicAdd(&plog[p][lane + 64], qc1 * ky);
    }
  }
  __syncthreads();

  // ---- softmax: every thread, both pixels (redundant across waves, no extra sync) ----
  float ax[9], ay[9];
  {
    float mx = -1e30f, my = -1e30f;
#pragma unroll
    for (int p = 0; p < 9; ++p) {
      ax[p] = plog[p][lane];
      ay[p] = plog[p][lane + 64];
      mx = fmaxf(mx, ax[p]); my = fmaxf(my, ay[p]);
    }
    float dx = 0.f, dy = 0.f;
#pragma unroll
    for (int p = 0; p < 9; ++p) {
      ax[p] = __expf(ax[p] - mx); dx += ax[p];
      ay[p] = __expf(ay[p] - my); dy += ay[p];
    }
    float ix = 1.f / dx, iy = 1.f / dy;
#pragma unroll
    for (int p = 0; p < 9; ++p) { ax[p] *= ix; ay[p] *= iy; }
  }

  // ---- V phase (both pixels) ----
  {
    float2 t[9];
#pragma unroll
    for (int dy = 0; dy < 3; ++dy)
#pragma unroll
      for (int dx = 0; dx < 3; ++dx)
        t[dy * 3 + dx] = hal2[8 + c][ly + dy][lx + dx];
    float ocx = 0.f, ocy = 0.f;
#pragma unroll
    for (int p = 0; p < 9; ++p) {
      float vx = Vb[p], vy = Vb[p];
#pragma unroll
      for (int rs = 0; rs < 9; ++rs) {
        vx = fmaf(Af[p * 9 + rs], t[rs].x, vx);
        vy = fmaf(Af[p * 9 + rs], t[rs].y, vy);
      }
      ocx = fmaf(ax[p], vx, ocx);
      ocy = fmaf(ay[p], vy, ocy);
    }
    ot[lane][c] = f2b(ocx);
    ot[lane + 64][c] = f2b(ocy);
  }
  __syncthreads();

  // ---- write aoT[b][s][j=n*8..n*8+7] (16B per pixel) ----
  if (c < 2) {
    int p = c * 64 + lane;
    uint4 val = *(const uint4*)&ot[p][0];
    int sp = (h0 + (p >> 4)) * 64 + w0 + (p & 15);
    *(uint4*)&aoT[((size_t)b * HW + sp) * 64 + n * 8] = val;
  }
}

// ---------------- K3: proj GEMM via bf16 MFMA ----------------
// out(256d x 128s per block) = pw(256x64) * aoT^T; K=64. 4 waves x 4 d-bands x 8 s-tiles.
__global__ __launch_bounds__(256) void proj_mfma(const unsigned short* __restrict__ aoT,
                                                 const unsigned short* __restrict__ pwf,
                                                 const float* __restrict__ pb,
                                                 float* __restrict__ out) {
  __shared__ unsigned short Bs[128 * 64];  // rows 128B, 8 chunks XOR-swizzled
  const int b = blockIdx.y;
  const int s_blk = blockIdx.x * 128;
  const int tid = threadIdx.x;
  const int wave = tid >> 6, lane = tid & 63;

  {
    const int slot = lane & 7, rsub = lane >> 3;
#pragma unroll
    for (int ii = 0; ii < 4; ++ii) {
      int i = wave * 4 + ii;
      int row = 8 * i + rsub;
      int mem_chunk = slot ^ rsub;
      const unsigned short* src =
          aoT + ((size_t)b * HW + s_blk + row) * 64 + mem_chunk * 8;
      async_copy16(src, (char*)Bs + i * 1024);
    }
  }
  __syncthreads();

  f32x4 acc[4][8];
#pragma unroll
  for (int t = 0; t < 4; ++t)
#pragma unroll
    for (int st = 0; st < 8; ++st) acc[t][st] = (f32x4){0.f, 0.f, 0.f, 0.f};

  const int n = lane & 15, g = lane >> 4;
#pragma unroll
  for (int c32 = 0; c32 < 2; ++c32) {
    bf16x8 af[4];
#pragma unroll
    for (int t = 0; t < 4; ++t) {
      int band = wave * 4 + t;
      af[t] = *(const bf16x8*)(pwf + ((size_t)(band * 2 + c32) * 64 + lane) * 8);
    }
#pragma unroll
    for (int st = 0; st < 8; ++st) {
      int s_row = st * 16 + n;
      int mc = c32 * 4 + g;
      int stc = mc ^ (s_row & 7);
      bf16x8 bf = *(const bf16x8*)&Bs[s_row * 64 + stc * 8];
#pragma unroll
      for (int t = 0; t < 4; ++t)
        acc[t][st] = __builtin_amdgcn_mfma_f32_16x16x32_bf16(af[t], bf, acc[t][st], 0, 0, 0);
    }
  }

  float bias[4][4];
#pragma unroll
  for (int t = 0; t < 4; ++t)
#pragma unroll
    for (int r = 0; r < 4; ++r) bias[t][r] = pb[(wave * 4 + t) * 16 + g * 4 + r];

  float* ob = out + ((size_t)b << 20);
#pragma unroll
  for (int t = 0; t < 4; ++t) {
    int d0 = (wave * 4 + t) * 16 + g * 4;
#pragma unroll
    for (int st = 0; st < 8; ++st) {
      int s = s_blk + st * 16 + n;
#pragma unroll
      for (int r = 0; r < 4; ++r)
        ob[(size_t)(d0 + r) * HW + s] = acc[t][st][r] + bias[t][r];
    }
  }
}

extern "C" void kernel_launch(void* const* d_in, const int* in_sizes, int n_in,
                              void* d_out, int out_size, void* d_ws, size_t ws_size,
                              hipStream_t stream) {
  (void)in_sizes; (void)n_in; (void)out_size; (void)ws_size;
  const float* x    = (const float*)d_in[0];
  const float* qw   = (const float*)d_in[5];
  const float* qb   = (const float*)d_in[6];
  const float* dcb  = (const float*)d_in[7];
  const float* w1   = (const float*)d_in[8];
  const float* dc1b = (const float*)d_in[9];
  const float* rpb  = (const float*)d_in[10];
  const float* pw   = (const float*)d_in[11];
  const float* pb   = (const float*)d_in[12];

  // Workspace (time-multiplexed, 64 MiB total = proven-safe R0 size):
  // [0, 25165824)            qkvt bf16 (B,192,4096)          qkv -> attn
  // [25165824, 33554432)     qwf (cast_qw -> qkv, dead after) THEN aoT bf16 (attn -> proj)
  // [33554432, 67108864)     xT bf16 (cast_xT -> qkv, dead)   THEN pwf (cast_pw -> proj)
  // prep (4224 B) lives at the head of d_out: written by cast_qw, read by attn,
  // dead before proj_mfma overwrites the full output buffer.
  unsigned short* qkvt = (unsigned short*)d_ws;
  unsigned short* qwf  = (unsigned short*)((char*)d_ws + 25165824);
  unsigned short* aoT  = (unsigned short*)((char*)d_ws + 25165824);
  unsigned short* xT   = (unsigned short*)((char*)d_ws + 33554432);
  unsigned short* pwf  = (unsigned short*)((char*)d_ws + 33554432);
  float* prep          = (float*)d_out;

  cast_qw<<<25, 256, 0, stream>>>(qw, qwf, dcb, w1, dc1b, rpb, prep);
  cast_xT<<<dim3(64, 4, BB), 256, 0, stream>>>(x, xT);
  qkv_mfma<<<dim3(32, BB), 256, 0, stream>>>(xT, qwf, qb, qkvt);
  cast_pw<<<8, 256, 0, stream>>>(pw, pwf);
  attn_kernel<<<dim3(BB * NHEAD, 32), 512, 0, stream>>>(qkvt, prep, aoT);
  proj_mfma<<<dim3(32, BB), 256, 0, stream>>>(aoT, pwf, pb, (float*)d_out);
}

// Round 3
// 377.854 us; speedup vs baseline: 1.0688x; 1.0688x over previous
//
#include <hip/hip_runtime.h>

#define BB 16
#define HW 4096
#define DIMC 256
#define NHEAD 8
#define CPH 8
#define NQKV 192
#define SCALE 0.17677669529663687f

typedef __attribute__((ext_vector_type(8))) short bf16x8;
typedef __attribute__((ext_vector_type(4))) float f32x4;

__device__ inline unsigned short f2b(float f) {
  union { float f; unsigned int u; } x; x.f = f;
  unsigned int r = x.u + 0x7FFFu + ((x.u >> 16) & 1u);
  return (unsigned short)(r >> 16);
}
__device__ inline float b2f(unsigned short u) {
  union { unsigned int u; float f; } x; x.u = ((unsigned int)u) << 16;
  return x.f;
}
__device__ inline void async_copy16(const void* g, void* l) {
  __builtin_amdgcn_global_load_lds((const __attribute__((address_space(1))) void*)g,
                                   (__attribute__((address_space(3))) void*)l, 16, 0, 0);
}

// ---------------- K0a: x (B,256k,4096s) fp32 -> xT (B,4096s,256k) bf16 ----------------
__global__ __launch_bounds__(256) void cast_xT(const float* __restrict__ x,
                                               unsigned short* __restrict__ xT) {
  __shared__ float Xs[64][69];
  const int b = blockIdx.z;
  const int k0 = blockIdx.y * 64;
  const int s0 = blockIdx.x * 64;
  const int tid = threadIdx.x;
  const float* xb = x + (size_t)b * (DIMC * HW);
#pragma unroll
  for (int i = 0; i < 4; ++i) {
    int idx = tid + i * 256;
    int kr = idx >> 4, f = idx & 15;
    float4 v = *(const float4*)&xb[(size_t)(k0 + kr) * HW + s0 + f * 4];
    Xs[kr][f * 4 + 0] = v.x; Xs[kr][f * 4 + 1] = v.y;
    Xs[kr][f * 4 + 2] = v.z; Xs[kr][f * 4 + 3] = v.w;
  }
  __syncthreads();
  unsigned short* ob = xT + (size_t)b * (HW * DIMC);
#pragma unroll
  for (int i = 0; i < 2; ++i) {
    int slot = tid + i * 256;
    int sr = slot >> 3, g8 = slot & 7;
    unsigned short pk[8];
#pragma unroll
    for (int j = 0; j < 8; ++j) pk[j] = f2b(Xs[g8 * 8 + j][sr]);
    *(uint4*)&ob[(size_t)(s0 + sr) * DIMC + k0 + g8 * 8] = *(uint4*)pk;
  }
}

// ---------------- K0b: qkv_w -> bf16 A-fragment-swizzled ; block 24 builds prep ----------------
// prep layout (floats): [0,864)   Afp[c][p][12] : (I + w1)[c][p][rs], 16B-aligned rows
//                       [864,960) Vb[c][12]     : dcb + dc1b
//                       [960,1056) Rb[n][12]    : rpb
__global__ __launch_bounds__(256) void cast_qw(const float* __restrict__ qw,
                                               unsigned short* __restrict__ qwf,
                                               const float* __restrict__ dcb,
                                               const float* __restrict__ w1,
                                               const float* __restrict__ dc1b,
                                               const float* __restrict__ rpb,
                                               float* __restrict__ prep) {
  if (blockIdx.x == 24) {
    for (int e = threadIdx.x; e < 1056; e += 256) {
      float v = 0.f;
      if (e < 864) {
        int cp = e / 12, rs = e - cp * 12;           // cp = c*9+p
        if (rs < 9) v = w1[cp * 9 + rs] + ((cp % 9) == rs ? 1.f : 0.f);
      } else if (e < 960) {
        int i = e - 864; int c = i / 12, p = i - c * 12;
        if (p < 9) v = dcb[c * 9 + p] + dc1b[c * 9 + p];
      } else {
        int i = e - 960; int n = i / 12, p = i - n * 12;
        if (p < 9) v = rpb[n * 9 + p];
      }
      prep[e] = v;
    }
    return;
  }
  int t = blockIdx.x * 256 + threadIdx.x;  // 6144
  int lane = t & 63;
  int cell = t >> 6;  // band*8 + c32
  int m = lane & 15, g = lane >> 4;
  int band = cell >> 3, c32 = cell & 7;
  int j = band * 16 + m;
  int k = c32 * 32 + g * 8;
  unsigned short pk[8];
#pragma unroll
  for (int i = 0; i < 8; ++i) pk[i] = f2b(qw[j * 256 + k + i]);
  *(uint4*)&qwf[(size_t)t * 8] = *(uint4*)pk;
}

// ---------------- K0c: proj_w (256,64) -> bf16 A-fragment-swizzled ----------------
__global__ __launch_bounds__(256) void cast_pw(const float* __restrict__ pw,
                                               unsigned short* __restrict__ pwf) {
  int t = blockIdx.x * 256 + threadIdx.x;  // 2048
  int lane = t & 63;
  int cell = t >> 6;  // band*2 + c32
  int m = lane & 15, g = lane >> 4;
  int band = cell >> 1, c32 = cell & 1;
  int d = band * 16 + m;
  int j = c32 * 32 + g * 8;
  unsigned short pk[8];
#pragma unroll
  for (int i = 0; i < 8; ++i) pk[i] = f2b(pw[d * 64 + j + i]);
  *(uint4*)&pwf[(size_t)t * 8] = *(uint4*)pk;
}

// ---------------- K1: qkv GEMM via bf16 MFMA ----------------
__global__ __launch_bounds__(256) void qkv_mfma(const unsigned short* __restrict__ xT,
                                                const unsigned short* __restrict__ qwf,
                                                const float* __restrict__ qb,
                                                unsigned short* __restrict__ qkvt) {
  __shared__ unsigned short Bs[128 * 256];
  const int b = blockIdx.y;
  const int s_blk = blockIdx.x * 128;
  const int tid = threadIdx.x;
  const int wave = tid >> 6, lane = tid & 63;

  {
    const int row_in = lane >> 5, cst = lane & 31;
#pragma unroll
    for (int ii = 0; ii < 16; ++ii) {
      int i = wave * 16 + ii;
      int s_row = 2 * i + row_in;
      int mem_chunk = (cst & 24) | ((cst ^ s_row) & 7);
      const unsigned short* src =
          xT + ((size_t)b * HW + s_blk + s_row) * DIMC + mem_chunk * 8;
      async_copy16(src, (char*)Bs + i * 1024);
    }
  }
  __syncthreads();

  f32x4 acc[3][8];
#pragma unroll
  for (int t = 0; t < 3; ++t)
#pragma unroll
    for (int st = 0; st < 8; ++st) acc[t][st] = (f32x4){0.f, 0.f, 0.f, 0.f};

  const int n = lane & 15, g = lane >> 4;
#pragma unroll
  for (int c32 = 0; c32 < 8; ++c32) {
    bf16x8 af[3];
#pragma unroll
    for (int t = 0; t < 3; ++t) {
      int band = wave * 3 + t;
      af[t] = *(const bf16x8*)(qwf + ((size_t)(band * 8 + c32) * 64 + lane) * 8);
    }
#pragma unroll
    for (int st = 0; st < 8; ++st) {
      int s_row = st * 16 + n;
      int mc = c32 * 4 + g;
      int stc = (mc & 24) | ((mc ^ s_row) & 7);
      bf16x8 bf = *(const bf16x8*)&Bs[s_row * 256 + stc * 8];
#pragma unroll
      for (int t = 0; t < 3; ++t)
        acc[t][st] = __builtin_amdgcn_mfma_f32_16x16x32_bf16(af[t], bf, acc[t][st], 0, 0, 0);
    }
  }

  unsigned short* ob = qkvt + (size_t)b * (NQKV * HW);
#pragma unroll
  for (int t = 0; t < 3; ++t) {
    int j0 = (wave * 3 + t) * 16 + g * 4;
#pragma unroll
    for (int st = 0; st < 8; ++st) {
      int s = s_blk + st * 16 + n;
#pragma unroll
      for (int r = 0; r < 4; ++r) {
        float v = acc[t][st][r] + qb[j0 + r];
        ob[(size_t)(j0 + r) * HW + s] = f2b(v);
      }
    }
  }
}

// ---------------- K2 v5: fused attn ----------------
// R1 post-mortem: Af[81] sourced from GLOBAL at 64 VGPR => remat/spill = global loads
// inside the FMA chain (VALUBusy 61->16.5%, 69->247us). Fix: A lives in LDS (wA) and is
// read IN-LOOP as wave-uniform broadcast ds_reads (R0-proven pattern, identity now
// pre-baked in prep). Keep R1 wins: plog atomicAdd single buffer, float2 halos, prep.
// Kb/Vb bases also staged to tiny LDS tables to keep live regs ~45 (no spill at 64).
// LDS ~26KB -> 4 blocks/CU (wave-capped) = ~100% occupancy vs R0's 38%.
__global__ __launch_bounds__(512, 4) void attn_kernel(const unsigned short* __restrict__ qkvt,
                                                      const float* __restrict__ prep,
                                                      unsigned short* __restrict__ aoT) {
  __shared__ float2 hal2[16][6][20];    // kk(0-7)/vv(8-15); [y][x] pairs (y, y+4). 15360 B
  __shared__ float plog[9][128];        // summed logits, atomically accumulated. 4608 B
  __shared__ __align__(16) float wA[8][108];  // (I+w1), 12-stride rows. 3456 B
  __shared__ float Kbs[8][12], Vbs[8][12];    // per-channel bases. 768 B
  __shared__ unsigned short ot[128][8]; // transpose buffer for aoT write. 2048 B

  const int bn = blockIdx.x;   // b*8+n
  const int tile = blockIdx.y; // 0..31 : 8 y-tiles x 4 x-tiles
  const int b = bn >> 3, n = bn & 7;
  const int h0 = (tile >> 2) * 8, w0 = (tile & 3) * 16;
  const int tid = threadIdx.x;
  const int c = tid >> 6, lane = tid & 63;
  const int ly = lane >> 4, lx = lane & 15;
  const int s0 = (h0 + ly) * 64 + (w0 + lx);
  const int s1 = s0 + 256;  // +4 rows
  const unsigned short* fb = qkvt + ((size_t)b * NQKV + n * 24) * HW;

  // zero logit accumulator
  for (int e = tid; e < 1152; e += 512) ((float*)plog)[e] = 0.f;

  // stage A (identity pre-baked) : 864 floats
  for (int e = tid; e < 864; e += 512) ((float*)wA)[e] = prep[e];

  // stage K/V bases: Vbs = dcb+dc1b, Kbs = Vbs + rpb[n]
  if (tid < 96) {
    int cc = tid / 12, p = tid - cc * 12;
    float d = prep[864 + tid];
    Vbs[cc][p] = d;
    Kbs[cc][p] = d + prep[960 + n * 12 + p];
  }

  // stage halos: 16 bufs x 10 rows x 18 cols -> float2 rows (y, y+4)
  for (int e = tid; e < 2880; e += 512) {
    int cb = e / 180;
    int rem = e - cb * 180;
    int y = rem / 18, xx = rem - y * 18;
    int gy = h0 - 1 + y, gx = w0 - 1 + xx;
    float v = 0.f;
    if ((unsigned)gy < 64u && (unsigned)gx < 64u)
      v = b2f(fb[(size_t)(8 + cb) * HW + gy * 64 + gx]);
    if (y < 6) hal2[cb][y][xx].x = v;
    if (y >= 4) hal2[cb][y - 4][xx].y = v;
  }

  float qc0 = SCALE * b2f(fb[(size_t)c * HW + s0]);
  float qc1 = SCALE * b2f(fb[(size_t)c * HW + s1]);
  __syncthreads();

  const float* wAc = &wA[c][0];

  // ---- K phase (both pixels), accumulate q*k into plog via LDS float atomics ----
  {
    float2 t[9];
#pragma unroll
    for (int dy = 0; dy < 3; ++dy)
#pragma unroll
      for (int dx = 0; dx < 3; ++dx)
        t[dy * 3 + dx] = hal2[c][ly + dy][lx + dx];
#pragma unroll
    for (int p = 0; p < 9; ++p) {
      float base = Kbs[c][p];
      float kx = base, ky = base;
#pragma unroll
      for (int rs = 0; rs < 9; ++rs) {
        float a = wAc[p * 12 + rs];
        kx = fmaf(a, t[rs].x, kx);
        ky = fmaf(a, t[rs].y, ky);
      }
      atomicAdd(&plog[p][lane], qc0 * kx);
      atomicAdd(&plog[p][lane + 64], qc1 * ky);
    }
  }
  __syncthreads();

  // ---- softmax: every thread, both pixels (redundant across waves, no extra sync) ----
  float ax[9], ay[9];
  {
    float mx = -1e30f, my = -1e30f;
#pragma unroll
    for (int p = 0; p < 9; ++p) {
      ax[p] = plog[p][lane];
      ay[p] = plog[p][lane + 64];
      mx = fmaxf(mx, ax[p]); my = fmaxf(my, ay[p]);
    }
    float dx = 0.f, dy = 0.f;
#pragma unroll
    for (int p = 0; p < 9; ++p) {
      ax[p] = __expf(ax[p] - mx); dx += ax[p];
      ay[p] = __expf(ay[p] - my); dy += ay[p];
    }
    float ix = 1.f / dx, iy = 1.f / dy;
#pragma unroll
    for (int p = 0; p < 9; ++p) { ax[p] *= ix; ay[p] *= iy; }
  }

  // ---- V phase (both pixels) ----
  {
    float2 t[9];
#pragma unroll
    for (int dy = 0; dy < 3; ++dy)
#pragma unroll
      for (int dx = 0; dx < 3; ++dx)
        t[dy * 3 + dx] = hal2[8 + c][ly + dy][lx + dx];
    float ocx = 0.f, ocy = 0.f;
#pragma unroll
    for (int p = 0; p < 9; ++p) {
      float base = Vbs[c][p];
      float vx = base, vy = base;
#pragma unroll
      for (int rs = 0; rs < 9; ++rs) {
        float a = wAc[p * 12 + rs];
        vx = fmaf(a, t[rs].x, vx);
        vy = fmaf(a, t[rs].y, vy);
      }
      ocx = fmaf(ax[p], vx, ocx);
      ocy = fmaf(ay[p], vy, ocy);
    }
    ot[lane][c] = f2b(ocx);
    ot[lane + 64][c] = f2b(ocy);
  }
  __syncthreads();

  // ---- write aoT[b][s][j=n*8..n*8+7] (16B per pixel) ----
  if (c < 2) {
    int p = c * 64 + lane;
    uint4 val = *(const uint4*)&ot[p][0];
    int sp = (h0 + (p >> 4)) * 64 + w0 + (p & 15);
    *(uint4*)&aoT[((size_t)b * HW + sp) * 64 + n * 8] = val;
  }
}

// ---------------- K3: proj GEMM via bf16 MFMA ----------------
// out(256d x 128s per block) = pw(256x64) * aoT^T; K=64. 4 waves x 4 d-bands x 8 s-tiles.
__global__ __launch_bounds__(256) void proj_mfma(const unsigned short* __restrict__ aoT,
                                                 const unsigned short* __restrict__ pwf,
                                                 const float* __restrict__ pb,
                                                 float* __restrict__ out) {
  __shared__ unsigned short Bs[128 * 64];  // rows 128B, 8 chunks XOR-swizzled
  const int b = blockIdx.y;
  const int s_blk = blockIdx.x * 128;
  const int tid = threadIdx.x;
  const int wave = tid >> 6, lane = tid & 63;

  {
    const int slot = lane & 7, rsub = lane >> 3;
#pragma unroll
    for (int ii = 0; ii < 4; ++ii) {
      int i = wave * 4 + ii;
      int row = 8 * i + rsub;
      int mem_chunk = slot ^ rsub;
      const unsigned short* src =
          aoT + ((size_t)b * HW + s_blk + row) * 64 + mem_chunk * 8;
      async_copy16(src, (char*)Bs + i * 1024);
    }
  }
  __syncthreads();

  f32x4 acc[4][8];
#pragma unroll
  for (int t = 0; t < 4; ++t)
#pragma unroll
    for (int st = 0; st < 8; ++st) acc[t][st] = (f32x4){0.f, 0.f, 0.f, 0.f};

  const int n = lane & 15, g = lane >> 4;
#pragma unroll
  for (int c32 = 0; c32 < 2; ++c32) {
    bf16x8 af[4];
#pragma unroll
    for (int t = 0; t < 4; ++t) {
      int band = wave * 4 + t;
      af[t] = *(const bf16x8*)(pwf + ((size_t)(band * 2 + c32) * 64 + lane) * 8);
    }
#pragma unroll
    for (int st = 0; st < 8; ++st) {
      int s_row = st * 16 + n;
      int mc = c32 * 4 + g;
      int stc = mc ^ (s_row & 7);
      bf16x8 bf = *(const bf16x8*)&Bs[s_row * 64 + stc * 8];
#pragma unroll
      for (int t = 0; t < 4; ++t)
        acc[t][st] = __builtin_amdgcn_mfma_f32_16x16x32_bf16(af[t], bf, acc[t][st], 0, 0, 0);
    }
  }

  float bias[4][4];
#pragma unroll
  for (int t = 0; t < 4; ++t)
#pragma unroll
    for (int r = 0; r < 4; ++r) bias[t][r] = pb[(wave * 4 + t) * 16 + g * 4 + r];

  float* ob = out + ((size_t)b << 20);
#pragma unroll
  for (int t = 0; t < 4; ++t) {
    int d0 = (wave * 4 + t) * 16 + g * 4;
#pragma unroll
    for (int st = 0; st < 8; ++st) {
      int s = s_blk + st * 16 + n;
#pragma unroll
      for (int r = 0; r < 4; ++r)
        ob[(size_t)(d0 + r) * HW + s] = acc[t][st][r] + bias[t][r];
    }
  }
}

extern "C" void kernel_launch(void* const* d_in, const int* in_sizes, int n_in,
                              void* d_out, int out_size, void* d_ws, size_t ws_size,
                              hipStream_t stream) {
  (void)in_sizes; (void)n_in; (void)out_size; (void)ws_size;
  const float* x    = (const float*)d_in[0];
  const float* qw   = (const float*)d_in[5];
  const float* qb   = (const float*)d_in[6];
  const float* dcb  = (const float*)d_in[7];
  const float* w1   = (const float*)d_in[8];
  const float* dc1b = (const float*)d_in[9];
  const float* rpb  = (const float*)d_in[10];
  const float* pw   = (const float*)d_in[11];
  const float* pb   = (const float*)d_in[12];

  // Workspace (time-multiplexed, 64 MiB total = proven-safe R0 size):
  // [0, 25165824)            qkvt bf16 (B,192,4096)          qkv -> attn
  // [25165824, 33554432)     qwf (cast_qw -> qkv, dead after) THEN aoT bf16 (attn -> proj)
  // [33554432, 67108864)     xT bf16 (cast_xT -> qkv, dead)   THEN pwf (cast_pw -> proj)
  // prep (4224 B) lives at the head of d_out: written by cast_qw, read by attn,
  // dead before proj_mfma overwrites the full output buffer.
  unsigned short* qkvt = (unsigned short*)d_ws;
  unsigned short* qwf  = (unsigned short*)((char*)d_ws + 25165824);
  unsigned short* aoT  = (unsigned short*)((char*)d_ws + 25165824);
  unsigned short* xT   = (unsigned short*)((char*)d_ws + 33554432);
  unsigned short* pwf  = (unsigned short*)((char*)d_ws + 33554432);
  float* prep          = (float*)d_out;

  cast_qw<<<25, 256, 0, stream>>>(qw, qwf, dcb, w1, dc1b, rpb, prep);
  cast_xT<<<dim3(64, 4, BB), 256, 0, stream>>>(x, xT);
  qkv_mfma<<<dim3(32, BB), 256, 0, stream>>>(xT, qwf, qb, qkvt);
  cast_pw<<<8, 256, 0, stream>>>(pw, pwf);
  attn_kernel<<<dim3(BB * NHEAD, 32), 512, 0, stream>>>(qkvt, prep, aoT);
  proj_mfma<<<dim3(32, BB), 256, 0, stream>>>(aoT, pwf, pb, (float*)d_out);
}

// Round 4
// 236.817 us; speedup vs baseline: 1.7054x; 1.5956x over previous
//
#include <hip/hip_runtime.h>

#define BB 16
#define HW 4096
#define DIMC 256
#define NHEAD 8
#define CPH 8
#define NQKV 192
#define SCALE 0.17677669529663687f

typedef __attribute__((ext_vector_type(8))) short bf16x8;
typedef __attribute__((ext_vector_type(4))) float f32x4;

__device__ inline unsigned short f2b(float f) {
  union { float f; unsigned int u; } x; x.f = f;
  unsigned int r = x.u + 0x7FFFu + ((x.u >> 16) & 1u);
  return (unsigned short)(r >> 16);
}
__device__ inline float b2f(unsigned short u) {
  union { unsigned int u; float f; } x; x.u = ((unsigned int)u) << 16;
  return x.f;
}
__device__ inline void async_copy16(const void* g, void* l) {
  __builtin_amdgcn_global_load_lds((const __attribute__((address_space(1))) void*)g,
                                   (__attribute__((address_space(3))) void*)l, 16, 0, 0);
}

// ---------------- K0a: x (B,256k,4096s) fp32 -> xT (B,4096s,256k) bf16 ----------------
__global__ __launch_bounds__(256) void cast_xT(const float* __restrict__ x,
                                               unsigned short* __restrict__ xT) {
  __shared__ float Xs[64][69];
  const int b = blockIdx.z;
  const int k0 = blockIdx.y * 64;
  const int s0 = blockIdx.x * 64;
  const int tid = threadIdx.x;
  const float* xb = x + (size_t)b * (DIMC * HW);
#pragma unroll
  for (int i = 0; i < 4; ++i) {
    int idx = tid + i * 256;
    int kr = idx >> 4, f = idx & 15;
    float4 v = *(const float4*)&xb[(size_t)(k0 + kr) * HW + s0 + f * 4];
    Xs[kr][f * 4 + 0] = v.x; Xs[kr][f * 4 + 1] = v.y;
    Xs[kr][f * 4 + 2] = v.z; Xs[kr][f * 4 + 3] = v.w;
  }
  __syncthreads();
  unsigned short* ob = xT + (size_t)b * (HW * DIMC);
#pragma unroll
  for (int i = 0; i < 2; ++i) {
    int slot = tid + i * 256;
    int sr = slot >> 3, g8 = slot & 7;
    unsigned short pk[8];
#pragma unroll
    for (int j = 0; j < 8; ++j) pk[j] = f2b(Xs[g8 * 8 + j][sr]);
    *(uint4*)&ob[(size_t)(s0 + sr) * DIMC + k0 + g8 * 8] = *(uint4*)pk;
  }
}

// ---------------- K0b: qkv_w -> bf16 A-fragment-swizzled ; block 24 builds prep ----------------
// prep layout (floats): [0,864)   Afp[c][p][12] : (I + w1)[c][p][rs], 16B-aligned rows
//                       [864,960) Vb[c][12]     : dcb + dc1b
//                       [960,1056) Rb[n][12]    : rpb
__global__ __launch_bounds__(256) void cast_qw(const float* __restrict__ qw,
                                               unsigned short* __restrict__ qwf,
                                               const float* __restrict__ dcb,
                                               const float* __restrict__ w1,
                                               const float* __restrict__ dc1b,
                                               const float* __restrict__ rpb,
                                               float* __restrict__ prep) {
  if (blockIdx.x == 24) {
    for (int e = threadIdx.x; e < 1056; e += 256) {
      float v = 0.f;
      if (e < 864) {
        int cp = e / 12, rs = e - cp * 12;           // cp = c*9+p
        if (rs < 9) v = w1[cp * 9 + rs] + ((cp % 9) == rs ? 1.f : 0.f);
      } else if (e < 960) {
        int i = e - 864; int c = i / 12, p = i - c * 12;
        if (p < 9) v = dcb[c * 9 + p] + dc1b[c * 9 + p];
      } else {
        int i = e - 960; int n = i / 12, p = i - n * 12;
        if (p < 9) v = rpb[n * 9 + p];
      }
      prep[e] = v;
    }
    return;
  }
  int t = blockIdx.x * 256 + threadIdx.x;  // 6144
  int lane = t & 63;
  int cell = t >> 6;  // band*8 + c32
  int m = lane & 15, g = lane >> 4;
  int band = cell >> 3, c32 = cell & 7;
  int j = band * 16 + m;
  int k = c32 * 32 + g * 8;
  unsigned short pk[8];
#pragma unroll
  for (int i = 0; i < 8; ++i) pk[i] = f2b(qw[j * 256 + k + i]);
  *(uint4*)&qwf[(size_t)t * 8] = *(uint4*)pk;
}

// ---------------- K0c: proj_w (256,64) -> bf16 A-fragment-swizzled ----------------
__global__ __launch_bounds__(256) void cast_pw(const float* __restrict__ pw,
                                               unsigned short* __restrict__ pwf) {
  int t = blockIdx.x * 256 + threadIdx.x;  // 2048
  int lane = t & 63;
  int cell = t >> 6;  // band*2 + c32
  int m = lane & 15, g = lane >> 4;
  int band = cell >> 1, c32 = cell & 1;
  int d = band * 16 + m;
  int j = c32 * 32 + g * 8;
  unsigned short pk[8];
#pragma unroll
  for (int i = 0; i < 8; ++i) pk[i] = f2b(pw[d * 64 + j + i]);
  *(uint4*)&pwf[(size_t)t * 8] = *(uint4*)pk;
}

// ---------------- K1: qkv GEMM via bf16 MFMA ----------------
__global__ __launch_bounds__(256) void qkv_mfma(const unsigned short* __restrict__ xT,
                                                const unsigned short* __restrict__ qwf,
                                                const float* __restrict__ qb,
                                                unsigned short* __restrict__ qkvt) {
  __shared__ unsigned short Bs[128 * 256];
  const int b = blockIdx.y;
  const int s_blk = blockIdx.x * 128;
  const int tid = threadIdx.x;
  const int wave = tid >> 6, lane = tid & 63;

  {
    const int row_in = lane >> 5, cst = lane & 31;
#pragma unroll
    for (int ii = 0; ii < 16; ++ii) {
      int i = wave * 16 + ii;
      int s_row = 2 * i + row_in;
      int mem_chunk = (cst & 24) | ((cst ^ s_row) & 7);
      const unsigned short* src =
          xT + ((size_t)b * HW + s_blk + s_row) * DIMC + mem_chunk * 8;
      async_copy16(src, (char*)Bs + i * 1024);
    }
  }
  __syncthreads();

  f32x4 acc[3][8];
#pragma unroll
  for (int t = 0; t < 3; ++t)
#pragma unroll
    for (int st = 0; st < 8; ++st) acc[t][st] = (f32x4){0.f, 0.f, 0.f, 0.f};

  const int n = lane & 15, g = lane >> 4;
#pragma unroll
  for (int c32 = 0; c32 < 8; ++c32) {
    bf16x8 af[3];
#pragma unroll
    for (int t = 0; t < 3; ++t) {
      int band = wave * 3 + t;
      af[t] = *(const bf16x8*)(qwf + ((size_t)(band * 8 + c32) * 64 + lane) * 8);
    }
#pragma unroll
    for (int st = 0; st < 8; ++st) {
      int s_row = st * 16 + n;
      int mc = c32 * 4 + g;
      int stc = (mc & 24) | ((mc ^ s_row) & 7);
      bf16x8 bf = *(const bf16x8*)&Bs[s_row * 256 + stc * 8];
#pragma unroll
      for (int t = 0; t < 3; ++t)
        acc[t][st] = __builtin_amdgcn_mfma_f32_16x16x32_bf16(af[t], bf, acc[t][st], 0, 0, 0);
    }
  }

  unsigned short* ob = qkvt + (size_t)b * (NQKV * HW);
#pragma unroll
  for (int t = 0; t < 3; ++t) {
    int j0 = (wave * 3 + t) * 16 + g * 4;
#pragma unroll
    for (int st = 0; st < 8; ++st) {
      int s = s_blk + st * 16 + n;
#pragma unroll
      for (int r = 0; r < 4; ++r) {
        float v = acc[t][st][r] + qb[j0 + r];
        ob[(size_t)(j0 + r) * HW + s] = f2b(v);
      }
    }
  }
}

// ---------------- K2 v6: fused attn, channel-in-wave + shuffle reduce ----------------
// R3 post-mortem: LDS atomicAdd logit accumulation serializes on the LDS atomic unit
// (VALU-busy time constant ~41us across R0/R1/R3; R1/R3 added ~160us pure stall).
// v6 removes cross-wave reduction entirely: lane = (pix<<3)|c, so all 8 channels of a
// pixel live in one wave; logit sum = 3-step __shfl_xor butterfly (masks 1,2,4).
// No plog, no atomics, no reduce pass, 2 barriers instead of 4. V phase needs no
// reduce (output is per-channel). Q staged via LDS for coalesced global reads.
// LDS ~26.2KB -> 4 blocks/CU (wave-capped).
__global__ __launch_bounds__(512, 4) void attn_kernel(const unsigned short* __restrict__ qkvt,
                                                      const float* __restrict__ prep,
                                                      unsigned short* __restrict__ aoT) {
  __shared__ float2 hal2[16][6][20];          // kk(0-7)/vv(8-15); (y, y+4) pairs. 15360 B
  __shared__ __align__(16) float wA[8][108];  // (I+w1), 12-stride rows. 3456 B
  __shared__ float Kbs[8][12], Vbs[8][12];    // per-channel bases. 768 B
  __shared__ float2 Qs2[8][72];               // q*SCALE, (set0,set1) pairs. 4608 B
  __shared__ unsigned short ot[128][8];       // transpose buffer for aoT write. 2048 B

  const int bn = blockIdx.x;   // b*8+n
  const int tile = blockIdx.y; // 0..31 : 8 y-tiles x 4 x-tiles
  const int b = bn >> 3, n = bn & 7;
  const int h0 = (tile >> 2) * 8, w0 = (tile & 3) * 16;
  const int tid = threadIdx.x;
  const int w = tid >> 6, lane = tid & 63;
  const int c = lane & 7;          // channel (within head)
  const int pi = lane >> 3;        // pixel-within-wave 0..7
  const int pidx = w * 8 + pi;     // pixel 0..63 within set
  const int pr = pidx >> 4;        // row 0..3 (set0); set1 = +4
  const int pc = pidx & 15;        // col 0..15
  const unsigned short* fb = qkvt + ((size_t)b * NQKV + n * 24) * HW;

  // stage A (identity pre-baked) : 864 floats
  for (int e = tid; e < 864; e += 512) ((float*)wA)[e] = prep[e];

  // stage K/V bases: Vbs = dcb+dc1b, Kbs = Vbs + rpb[n]
  if (tid < 96) {
    int cc = tid / 12, p = tid - cc * 12;
    float d = prep[864 + tid];
    Vbs[cc][p] = d;
    Kbs[cc][p] = d + prep[960 + n * 12 + p];
  }

  // stage q tile: 8 ch x 64 px x 2 sets, coalesced, pre-scaled
  {
    int cq = tid >> 6, px = tid & 63;
    int sp = (h0 + (px >> 4)) * 64 + w0 + (px & 15);
    float v0 = b2f(fb[(size_t)cq * HW + sp]);
    float v1 = b2f(fb[(size_t)cq * HW + sp + 256]);
    Qs2[cq][px] = make_float2(SCALE * v0, SCALE * v1);
  }

  // stage halos: 16 bufs x 10 rows x 18 cols -> float2 rows (y, y+4)
  for (int e = tid; e < 2880; e += 512) {
    int cb = e / 180;
    int rem = e - cb * 180;
    int y = rem / 18, xx = rem - y * 18;
    int gy = h0 - 1 + y, gx = w0 - 1 + xx;
    float v = 0.f;
    if ((unsigned)gy < 64u && (unsigned)gx < 64u)
      v = b2f(fb[(size_t)(8 + cb) * HW + gy * 64 + gx]);
    if (y < 6) hal2[cb][y][xx].x = v;
    if (y >= 4) hal2[cb][y - 4][xx].y = v;
  }
  __syncthreads();

  const float* wAc = &wA[c][0];
  const float2 qc = Qs2[c][pidx];

  // ---- K phase: per-lane channel partials, butterfly-summed over c (masks 1,2,4) ----
  float ax[9], ay[9];
  {
    float2 t[9];
#pragma unroll
    for (int dy = 0; dy < 3; ++dy)
#pragma unroll
      for (int dx = 0; dx < 3; ++dx)
        t[dy * 3 + dx] = hal2[c][pr + dy][pc + dx];
#pragma unroll
    for (int p = 0; p < 9; ++p) {
      float base = Kbs[c][p];
      float kx = base, ky = base;
#pragma unroll
      for (int rs = 0; rs < 9; ++rs) {
        float a = wAc[p * 12 + rs];
        kx = fmaf(a, t[rs].x, kx);
        ky = fmaf(a, t[rs].y, ky);
      }
      float lx = qc.x * kx;
      float lyv = qc.y * ky;
      lx += __shfl_xor(lx, 1);  lyv += __shfl_xor(lyv, 1);
      lx += __shfl_xor(lx, 2);  lyv += __shfl_xor(lyv, 2);
      lx += __shfl_xor(lx, 4);  lyv += __shfl_xor(lyv, 4);
      ax[p] = lx; ay[p] = lyv;
    }
  }

  // ---- softmax: per-lane over p (redundant across the 8 channel-lanes, no sync) ----
  {
    float mx = -1e30f, my = -1e30f;
#pragma unroll
    for (int p = 0; p < 9; ++p) { mx = fmaxf(mx, ax[p]); my = fmaxf(my, ay[p]); }
    float dx = 0.f, dy = 0.f;
#pragma unroll
    for (int p = 0; p < 9; ++p) {
      ax[p] = __expf(ax[p] - mx); dx += ax[p];
      ay[p] = __expf(ay[p] - my); dy += ay[p];
    }
    float ix = 1.f / dx, iy = 1.f / dy;
#pragma unroll
    for (int p = 0; p < 9; ++p) { ax[p] *= ix; ay[p] *= iy; }
  }

  // ---- V phase: per-channel output, no reduce needed ----
  {
    float2 t[9];
#pragma unroll
    for (int dy = 0; dy < 3; ++dy)
#pragma unroll
      for (int dx = 0; dx < 3; ++dx)
        t[dy * 3 + dx] = hal2[8 + c][pr + dy][pc + dx];
    float ocx = 0.f, ocy = 0.f;
#pragma unroll
    for (int p = 0; p < 9; ++p) {
      float base = Vbs[c][p];
      float vx = base, vy = base;
#pragma unroll
      for (int rs = 0; rs < 9; ++rs) {
        float a = wAc[p * 12 + rs];
        vx = fmaf(a, t[rs].x, vx);
        vy = fmaf(a, t[rs].y, vy);
      }
      ocx = fmaf(ax[p], vx, ocx);
      ocy = fmaf(ay[p], vy, ocy);
    }
    ot[pidx][c] = f2b(ocx);
    ot[pidx + 64][c] = f2b(ocy);
  }
  __syncthreads();

  // ---- write aoT[b][s][j=n*8..n*8+7] (16B per pixel) ----
  if (w < 2) {
    int p = w * 64 + lane;
    uint4 val = *(const uint4*)&ot[p][0];
    int sp = (h0 + (p >> 4)) * 64 + w0 + (p & 15);
    *(uint4*)&aoT[((size_t)b * HW + sp) * 64 + n * 8] = val;
  }
}

// ---------------- K3: proj GEMM via bf16 MFMA ----------------
// out(256d x 128s per block) = pw(256x64) * aoT^T; K=64. 4 waves x 4 d-bands x 8 s-tiles.
__global__ __launch_bounds__(256) void proj_mfma(const unsigned short* __restrict__ aoT,
                                                 const unsigned short* __restrict__ pwf,
                                                 const float* __restrict__ pb,
                                                 float* __restrict__ out) {
  __shared__ unsigned short Bs[128 * 64];  // rows 128B, 8 chunks XOR-swizzled
  const int b = blockIdx.y;
  const int s_blk = blockIdx.x * 128;
  const int tid = threadIdx.x;
  const int wave = tid >> 6, lane = tid & 63;

  {
    const int slot = lane & 7, rsub = lane >> 3;
#pragma unroll
    for (int ii = 0; ii < 4; ++ii) {
      int i = wave * 4 + ii;
      int row = 8 * i + rsub;
      int mem_chunk = slot ^ rsub;
      const unsigned short* src =
          aoT + ((size_t)b * HW + s_blk + row) * 64 + mem_chunk * 8;
      async_copy16(src, (char*)Bs + i * 1024);
    }
  }
  __syncthreads();

  f32x4 acc[4][8];
#pragma unroll
  for (int t = 0; t < 4; ++t)
#pragma unroll
    for (int st = 0; st < 8; ++st) acc[t][st] = (f32x4){0.f, 0.f, 0.f, 0.f};

  const int n = lane & 15, g = lane >> 4;
#pragma unroll
  for (int c32 = 0; c32 < 2; ++c32) {
    bf16x8 af[4];
#pragma unroll
    for (int t = 0; t < 4; ++t) {
      int band = wave * 4 + t;
      af[t] = *(const bf16x8*)(pwf + ((size_t)(band * 2 + c32) * 64 + lane) * 8);
    }
#pragma unroll
    for (int st = 0; st < 8; ++st) {
      int s_row = st * 16 + n;
      int mc = c32 * 4 + g;
      int stc = mc ^ (s_row & 7);
      bf16x8 bf = *(const bf16x8*)&Bs[s_row * 64 + stc * 8];
#pragma unroll
      for (int t = 0; t < 4; ++t)
        acc[t][st] = __builtin_amdgcn_mfma_f32_16x16x32_bf16(af[t], bf, acc[t][st], 0, 0, 0);
    }
  }

  float bias[4][4];
#pragma unroll
  for (int t = 0; t < 4; ++t)
#pragma unroll
    for (int r = 0; r < 4; ++r) bias[t][r] = pb[(wave * 4 + t) * 16 + g * 4 + r];

  float* ob = out + ((size_t)b << 20);
#pragma unroll
  for (int t = 0; t < 4; ++t) {
    int d0 = (wave * 4 + t) * 16 + g * 4;
#pragma unroll
    for (int st = 0; st < 8; ++st) {
      int s = s_blk + st * 16 + n;
#pragma unroll
      for (int r = 0; r < 4; ++r)
        ob[(size_t)(d0 + r) * HW + s] = acc[t][st][r] + bias[t][r];
    }
  }
}

extern "C" void kernel_launch(void* const* d_in, const int* in_sizes, int n_in,
                              void* d_out, int out_size, void* d_ws, size_t ws_size,
                              hipStream_t stream) {
  (void)in_sizes; (void)n_in; (void)out_size; (void)ws_size;
  const float* x    = (const float*)d_in[0];
  const float* qw   = (const float*)d_in[5];
  const float* qb   = (const float*)d_in[6];
  const float* dcb  = (const float*)d_in[7];
  const float* w1   = (const float*)d_in[8];
  const float* dc1b = (const float*)d_in[9];
  const float* rpb  = (const float*)d_in[10];
  const float* pw   = (const float*)d_in[11];
  const float* pb   = (const float*)d_in[12];

  // Workspace (time-multiplexed, 64 MiB total = proven-safe R0 size):
  // [0, 25165824)            qkvt bf16 (B,192,4096)          qkv -> attn
  // [25165824, 33554432)     qwf (cast_qw -> qkv, dead after) THEN aoT bf16 (attn -> proj)
  // [33554432, 67108864)     xT bf16 (cast_xT -> qkv, dead)   THEN pwf (cast_pw -> proj)
  // prep (4224 B) lives at the head of d_out: written by cast_qw, read by attn,
  // dead before proj_mfma overwrites the full output buffer.
  unsigned short* qkvt = (unsigned short*)d_ws;
  unsigned short* qwf  = (unsigned short*)((char*)d_ws + 25165824);
  unsigned short* aoT  = (unsigned short*)((char*)d_ws + 25165824);
  unsigned short* xT   = (unsigned short*)((char*)d_ws + 33554432);
  unsigned short* pwf  = (unsigned short*)((char*)d_ws + 33554432);
  float* prep          = (float*)d_out;

  cast_qw<<<25, 256, 0, stream>>>(qw, qwf, dcb, w1, dc1b, rpb, prep);
  cast_xT<<<dim3(64, 4, BB), 256, 0, stream>>>(x, xT);
  qkv_mfma<<<dim3(32, BB), 256, 0, stream>>>(xT, qwf, qb, qkvt);
  cast_pw<<<8, 256, 0, stream>>>(pw, pwf);
  attn_kernel<<<dim3(BB * NHEAD, 32), 512, 0, stream>>>(qkvt, prep, aoT);
  proj_mfma<<<dim3(32, BB), 256, 0, stream>>>(aoT, pwf, pb, (float*)d_out);
}

// Round 5
// 227.588 us; speedup vs baseline: 1.7745x; 1.0405x over previous
//
#include <hip/hip_runtime.h>

#define BB 16
#define HW 4096
#define DIMC 256
#define NHEAD 8
#define CPH 8
#define NQKV 192
#define SCALE 0.17677669529663687f

typedef __attribute__((ext_vector_type(8))) short bf16x8;
typedef __attribute__((ext_vector_type(4))) float f32x4;

__device__ inline unsigned short f2b(float f) {
  union { float f; unsigned int u; } x; x.f = f;
  unsigned int r = x.u + 0x7FFFu + ((x.u >> 16) & 1u);
  return (unsigned short)(r >> 16);
}
__device__ inline float b2f(unsigned short u) {
  union { unsigned int u; float f; } x; x.u = ((unsigned int)u) << 16;
  return x.f;
}
__device__ inline void async_copy16(const void* g, void* l) {
  __builtin_amdgcn_global_load_lds((const __attribute__((address_space(1))) void*)g,
                                   (__attribute__((address_space(3))) void*)l, 16, 0, 0);
}

// ---------------- K0a: x (B,256k,4096s) fp32 -> xT (B,4096s,256k) bf16 ----------------
__global__ __launch_bounds__(256) void cast_xT(const float* __restrict__ x,
                                               unsigned short* __restrict__ xT) {
  __shared__ float Xs[64][69];
  const int b = blockIdx.z;
  const int k0 = blockIdx.y * 64;
  const int s0 = blockIdx.x * 64;
  const int tid = threadIdx.x;
  const float* xb = x + (size_t)b * (DIMC * HW);
#pragma unroll
  for (int i = 0; i < 4; ++i) {
    int idx = tid + i * 256;
    int kr = idx >> 4, f = idx & 15;
    float4 v = *(const float4*)&xb[(size_t)(k0 + kr) * HW + s0 + f * 4];
    Xs[kr][f * 4 + 0] = v.x; Xs[kr][f * 4 + 1] = v.y;
    Xs[kr][f * 4 + 2] = v.z; Xs[kr][f * 4 + 3] = v.w;
  }
  __syncthreads();
  unsigned short* ob = xT + (size_t)b * (HW * DIMC);
#pragma unroll
  for (int i = 0; i < 2; ++i) {
    int slot = tid + i * 256;
    int sr = slot >> 3, g8 = slot & 7;
    unsigned short pk[8];
#pragma unroll
    for (int j = 0; j < 8; ++j) pk[j] = f2b(Xs[g8 * 8 + j][sr]);
    *(uint4*)&ob[(size_t)(s0 + sr) * DIMC + k0 + g8 * 8] = *(uint4*)pk;
  }
}

// ---------------- K0b: qkv_w -> bf16 A-fragment-swizzled ; block 24 builds prep ----------------
// prep layout (floats): [0,864)   Afp[c][p][12] : (I + w1)[c][p][rs], 16B-aligned rows
//                       [864,960) Vb[c][12]     : dcb + dc1b
//                       [960,1056) Rb[n][12]    : rpb
__global__ __launch_bounds__(256) void cast_qw(const float* __restrict__ qw,
                                               unsigned short* __restrict__ qwf,
                                               const float* __restrict__ dcb,
                                               const float* __restrict__ w1,
                                               const float* __restrict__ dc1b,
                                               const float* __restrict__ rpb,
                                               float* __restrict__ prep) {
  if (blockIdx.x == 24) {
    for (int e = threadIdx.x; e < 1056; e += 256) {
      float v = 0.f;
      if (e < 864) {
        int cp = e / 12, rs = e - cp * 12;           // cp = c*9+p
        if (rs < 9) v = w1[cp * 9 + rs] + ((cp % 9) == rs ? 1.f : 0.f);
      } else if (e < 960) {
        int i = e - 864; int c = i / 12, p = i - c * 12;
        if (p < 9) v = dcb[c * 9 + p] + dc1b[c * 9 + p];
      } else {
        int i = e - 960; int n = i / 12, p = i - n * 12;
        if (p < 9) v = rpb[n * 9 + p];
      }
      prep[e] = v;
    }
    return;
  }
  int t = blockIdx.x * 256 + threadIdx.x;  // 6144
  int lane = t & 63;
  int cell = t >> 6;  // band*8 + c32
  int m = lane & 15, g = lane >> 4;
  int band = cell >> 3, c32 = cell & 7;
  int j = band * 16 + m;
  int k = c32 * 32 + g * 8;
  unsigned short pk[8];
#pragma unroll
  for (int i = 0; i < 8; ++i) pk[i] = f2b(qw[j * 256 + k + i]);
  *(uint4*)&qwf[(size_t)t * 8] = *(uint4*)pk;
}

// ---------------- K0c: proj_w (256,64) -> bf16 A-fragment-swizzled ----------------
__global__ __launch_bounds__(256) void cast_pw(const float* __restrict__ pw,
                                               unsigned short* __restrict__ pwf) {
  int t = blockIdx.x * 256 + threadIdx.x;  // 2048
  int lane = t & 63;
  int cell = t >> 6;  // band*2 + c32
  int m = lane & 15, g = lane >> 4;
  int band = cell >> 1, c32 = cell & 1;
  int d = band * 16 + m;
  int j = c32 * 32 + g * 8;
  unsigned short pk[8];
#pragma unroll
  for (int i = 0; i < 8; ++i) pk[i] = f2b(pw[d * 64 + j + i]);
  *(uint4*)&pwf[(size_t)t * 8] = *(uint4*)pk;
}

// ---------------- K1: qkv GEMM via bf16 MFMA ----------------
__global__ __launch_bounds__(256) void qkv_mfma(const unsigned short* __restrict__ xT,
                                                const unsigned short* __restrict__ qwf,
                                                const float* __restrict__ qb,
                                                unsigned short* __restrict__ qkvt) {
  __shared__ unsigned short Bs[128 * 256];
  const int b = blockIdx.y;
  const int s_blk = blockIdx.x * 128;
  const int tid = threadIdx.x;
  const int wave = tid >> 6, lane = tid & 63;

  {
    const int row_in = lane >> 5, cst = lane & 31;
#pragma unroll
    for (int ii = 0; ii < 16; ++ii) {
      int i = wave * 16 + ii;
      int s_row = 2 * i + row_in;
      int mem_chunk = (cst & 24) | ((cst ^ s_row) & 7);
      const unsigned short* src =
          xT + ((size_t)b * HW + s_blk + s_row) * DIMC + mem_chunk * 8;
      async_copy16(src, (char*)Bs + i * 1024);
    }
  }
  __syncthreads();

  f32x4 acc[3][8];
#pragma unroll
  for (int t = 0; t < 3; ++t)
#pragma unroll
    for (int st = 0; st < 8; ++st) acc[t][st] = (f32x4){0.f, 0.f, 0.f, 0.f};

  const int n = lane & 15, g = lane >> 4;
#pragma unroll
  for (int c32 = 0; c32 < 8; ++c32) {
    bf16x8 af[3];
#pragma unroll
    for (int t = 0; t < 3; ++t) {
      int band = wave * 3 + t;
      af[t] = *(const bf16x8*)(qwf + ((size_t)(band * 8 + c32) * 64 + lane) * 8);
    }
#pragma unroll
    for (int st = 0; st < 8; ++st) {
      int s_row = st * 16 + n;
      int mc = c32 * 4 + g;
      int stc = (mc & 24) | ((mc ^ s_row) & 7);
      bf16x8 bf = *(const bf16x8*)&Bs[s_row * 256 + stc * 8];
#pragma unroll
      for (int t = 0; t < 3; ++t)
        acc[t][st] = __builtin_amdgcn_mfma_f32_16x16x32_bf16(af[t], bf, acc[t][st], 0, 0, 0);
    }
  }

  unsigned short* ob = qkvt + (size_t)b * (NQKV * HW);
#pragma unroll
  for (int t = 0; t < 3; ++t) {
    int j0 = (wave * 3 + t) * 16 + g * 4;
#pragma unroll
    for (int st = 0; st < 8; ++st) {
      int s = s_blk + st * 16 + n;
#pragma unroll
      for (int r = 0; r < 4; ++r) {
        float v = acc[t][st][r] + qb[j0 + r];
        ob[(size_t)(j0 + r) * HW + s] = f2b(v);
      }
    }
  }
}

// ---------------- K2 v7: channel-in-wave + shuffle reduce, bank-conflict-free halos ----
// R4 post-mortem: structure worked (atomics gone, 225->78us) but hal2 channel stride
// was 240 dwords = 16 mod 32 -> channels c,c+2 on identical banks -> 4-way conflict on
// every halo b64 read (SQ_LDS_BANK_CONFLICT 7.2M, ~12us/CU serialized).
// v7: pad halo row 20->21 float2. Channel stride 252 dwords = 28 mod 32; a 16-lane
// phase (8ch x 2px) hits bank-pair starts {28c}+{0,2} = all 32 banks exactly once ->
// conflict-free. Qs2 72->73 (stride 146 = 18 mod 32, distinct). No other changes.
__global__ __launch_bounds__(512, 4) void attn_kernel(const unsigned short* __restrict__ qkvt,
                                                      const float* __restrict__ prep,
                                                      unsigned short* __restrict__ aoT) {
  __shared__ float2 hal2[16][6][21];          // kk(0-7)/vv(8-15); (y, y+4) pairs. 16128 B
  __shared__ __align__(16) float wA[8][108];  // (I+w1), 12-stride rows. 3456 B
  __shared__ float Kbs[8][12], Vbs[8][12];    // per-channel bases. 768 B
  __shared__ float2 Qs2[8][73];               // q*SCALE, (set0,set1) pairs. 4672 B
  __shared__ unsigned short ot[128][8];       // transpose buffer for aoT write. 2048 B

  const int bn = blockIdx.x;   // b*8+n
  const int tile = blockIdx.y; // 0..31 : 8 y-tiles x 4 x-tiles
  const int b = bn >> 3, n = bn & 7;
  const int h0 = (tile >> 2) * 8, w0 = (tile & 3) * 16;
  const int tid = threadIdx.x;
  const int w = tid >> 6, lane = tid & 63;
  const int c = lane & 7;          // channel (within head)
  const int pi = lane >> 3;        // pixel-within-wave 0..7
  const int pidx = w * 8 + pi;     // pixel 0..63 within set
  const int pr = pidx >> 4;        // row 0..3 (set0); set1 = +4
  const int pc = pidx & 15;        // col 0..15
  const unsigned short* fb = qkvt + ((size_t)b * NQKV + n * 24) * HW;

  // stage A (identity pre-baked) : 864 floats
  for (int e = tid; e < 864; e += 512) ((float*)wA)[e] = prep[e];

  // stage K/V bases: Vbs = dcb+dc1b, Kbs = Vbs + rpb[n]
  if (tid < 96) {
    int cc = tid / 12, p = tid - cc * 12;
    float d = prep[864 + tid];
    Vbs[cc][p] = d;
    Kbs[cc][p] = d + prep[960 + n * 12 + p];
  }

  // stage q tile: 8 ch x 64 px x 2 sets, coalesced, pre-scaled
  {
    int cq = tid >> 6, px = tid & 63;
    int sp = (h0 + (px >> 4)) * 64 + w0 + (px & 15);
    float v0 = b2f(fb[(size_t)cq * HW + sp]);
    float v1 = b2f(fb[(size_t)cq * HW + sp + 256]);
    Qs2[cq][px] = make_float2(SCALE * v0, SCALE * v1);
  }

  // stage halos: 16 bufs x 10 rows x 18 cols -> float2 rows (y, y+4)
  for (int e = tid; e < 2880; e += 512) {
    int cb = e / 180;
    int rem = e - cb * 180;
    int y = rem / 18, xx = rem - y * 18;
    int gy = h0 - 1 + y, gx = w0 - 1 + xx;
    float v = 0.f;
    if ((unsigned)gy < 64u && (unsigned)gx < 64u)
      v = b2f(fb[(size_t)(8 + cb) * HW + gy * 64 + gx]);
    if (y < 6) hal2[cb][y][xx].x = v;
    if (y >= 4) hal2[cb][y - 4][xx].y = v;
  }
  __syncthreads();

  const float* wAc = &wA[c][0];
  const float2 qc = Qs2[c][pidx];

  // ---- K phase: per-lane channel partials, butterfly-summed over c (masks 1,2,4) ----
  float ax[9], ay[9];
  {
    float2 t[9];
#pragma unroll
    for (int dy = 0; dy < 3; ++dy)
#pragma unroll
      for (int dx = 0; dx < 3; ++dx)
        t[dy * 3 + dx] = hal2[c][pr + dy][pc + dx];
#pragma unroll
    for (int p = 0; p < 9; ++p) {
      float base = Kbs[c][p];
      float kx = base, ky = base;
#pragma unroll
      for (int rs = 0; rs < 9; ++rs) {
        float a = wAc[p * 12 + rs];
        kx = fmaf(a, t[rs].x, kx);
        ky = fmaf(a, t[rs].y, ky);
      }
      float lx = qc.x * kx;
      float lyv = qc.y * ky;
      lx += __shfl_xor(lx, 1);  lyv += __shfl_xor(lyv, 1);
      lx += __shfl_xor(lx, 2);  lyv += __shfl_xor(lyv, 2);
      lx += __shfl_xor(lx, 4);  lyv += __shfl_xor(lyv, 4);
      ax[p] = lx; ay[p] = lyv;
    }
  }

  // ---- softmax: per-lane over p (redundant across the 8 channel-lanes, no sync) ----
  {
    float mx = -1e30f, my = -1e30f;
#pragma unroll
    for (int p = 0; p < 9; ++p) { mx = fmaxf(mx, ax[p]); my = fmaxf(my, ay[p]); }
    float dx = 0.f, dy = 0.f;
#pragma unroll
    for (int p = 0; p < 9; ++p) {
      ax[p] = __expf(ax[p] - mx); dx += ax[p];
      ay[p] = __expf(ay[p] - my); dy += ay[p];
    }
    float ix = 1.f / dx, iy = 1.f / dy;
#pragma unroll
    for (int p = 0; p < 9; ++p) { ax[p] *= ix; ay[p] *= iy; }
  }

  // ---- V phase: per-channel output, no reduce needed ----
  {
    float2 t[9];
#pragma unroll
    for (int dy = 0; dy < 3; ++dy)
#pragma unroll
      for (int dx = 0; dx < 3; ++dx)
        t[dy * 3 + dx] = hal2[8 + c][pr + dy][pc + dx];
    float ocx = 0.f, ocy = 0.f;
#pragma unroll
    for (int p = 0; p < 9; ++p) {
      float base = Vbs[c][p];
      float vx = base, vy = base;
#pragma unroll
      for (int rs = 0; rs < 9; ++rs) {
        float a = wAc[p * 12 + rs];
        vx = fmaf(a, t[rs].x, vx);
        vy = fmaf(a, t[rs].y, vy);
      }
      ocx = fmaf(ax[p], vx, ocx);
      ocy = fmaf(ay[p], vy, ocy);
    }
    ot[pidx][c] = f2b(ocx);
    ot[pidx + 64][c] = f2b(ocy);
  }
  __syncthreads();

  // ---- write aoT[b][s][j=n*8..n*8+7] (16B per pixel) ----
  if (w < 2) {
    int p = w * 64 + lane;
    uint4 val = *(const uint4*)&ot[p][0];
    int sp = (h0 + (p >> 4)) * 64 + w0 + (p & 15);
    *(uint4*)&aoT[((size_t)b * HW + sp) * 64 + n * 8] = val;
  }
}

// ---------------- K3: proj GEMM via bf16 MFMA ----------------
// out(256d x 128s per block) = pw(256x64) * aoT^T; K=64. 4 waves x 4 d-bands x 8 s-tiles.
__global__ __launch_bounds__(256) void proj_mfma(const unsigned short* __restrict__ aoT,
                                                 const unsigned short* __restrict__ pwf,
                                                 const float* __restrict__ pb,
                                                 float* __restrict__ out) {
  __shared__ unsigned short Bs[128 * 64];  // rows 128B, 8 chunks XOR-swizzled
  const int b = blockIdx.y;
  const int s_blk = blockIdx.x * 128;
  const int tid = threadIdx.x;
  const int wave = tid >> 6, lane = tid & 63;

  {
    const int slot = lane & 7, rsub = lane >> 3;
#pragma unroll
    for (int ii = 0; ii < 4; ++ii) {
      int i = wave * 4 + ii;
      int row = 8 * i + rsub;
      int mem_chunk = slot ^ rsub;
      const unsigned short* src =
          aoT + ((size_t)b * HW + s_blk + row) * 64 + mem_chunk * 8;
      async_copy16(src, (char*)Bs + i * 1024);
    }
  }
  __syncthreads();

  f32x4 acc[4][8];
#pragma unroll
  for (int t = 0; t < 4; ++t)
#pragma unroll
    for (int st = 0; st < 8; ++st) acc[t][st] = (f32x4){0.f, 0.f, 0.f, 0.f};

  const int n = lane & 15, g = lane >> 4;
#pragma unroll
  for (int c32 = 0; c32 < 2; ++c32) {
    bf16x8 af[4];
#pragma unroll
    for (int t = 0; t < 4; ++t) {
      int band = wave * 4 + t;
      af[t] = *(const bf16x8*)(pwf + ((size_t)(band * 2 + c32) * 64 + lane) * 8);
    }
#pragma unroll
    for (int st = 0; st < 8; ++st) {
      int s_row = st * 16 + n;
      int mc = c32 * 4 + g;
      int stc = mc ^ (s_row & 7);
      bf16x8 bf = *(const bf16x8*)&Bs[s_row * 64 + stc * 8];
#pragma unroll
      for (int t = 0; t < 4; ++t)
        acc[t][st] = __builtin_amdgcn_mfma_f32_16x16x32_bf16(af[t], bf, acc[t][st], 0, 0, 0);
    }
  }

  float bias[4][4];
#pragma unroll
  for (int t = 0; t < 4; ++t)
#pragma unroll
    for (int r = 0; r < 4; ++r) bias[t][r] = pb[(wave * 4 + t) * 16 + g * 4 + r];

  float* ob = out + ((size_t)b << 20);
#pragma unroll
  for (int t = 0; t < 4; ++t) {
    int d0 = (wave * 4 + t) * 16 + g * 4;
#pragma unroll
    for (int st = 0; st < 8; ++st) {
      int s = s_blk + st * 16 + n;
#pragma unroll
      for (int r = 0; r < 4; ++r)
        ob[(size_t)(d0 + r) * HW + s] = acc[t][st][r] + bias[t][r];
    }
  }
}

extern "C" void kernel_launch(void* const* d_in, const int* in_sizes, int n_in,
                              void* d_out, int out_size, void* d_ws, size_t ws_size,
                              hipStream_t stream) {
  (void)in_sizes; (void)n_in; (void)out_size; (void)ws_size;
  const float* x    = (const float*)d_in[0];
  const float* qw   = (const float*)d_in[5];
  const float* qb   = (const float*)d_in[6];
  const float* dcb  = (const float*)d_in[7];
  const float* w1   = (const float*)d_in[8];
  const float* dc1b = (const float*)d_in[9];
  const float* rpb  = (const float*)d_in[10];
  const float* pw   = (const float*)d_in[11];
  const float* pb   = (const float*)d_in[12];

  // Workspace (time-multiplexed, 64 MiB total = proven-safe R0 size):
  // [0, 25165824)            qkvt bf16 (B,192,4096)          qkv -> attn
  // [25165824, 33554432)     qwf (cast_qw -> qkv, dead after) THEN aoT bf16 (attn -> proj)
  // [33554432, 67108864)     xT bf16 (cast_xT -> qkv, dead)   THEN pwf (cast_pw -> proj)
  // prep (4224 B) lives at the head of d_out: written by cast_qw, read by attn,
  // dead before proj_mfma overwrites the full output buffer.
  unsigned short* qkvt = (unsigned short*)d_ws;
  unsigned short* qwf  = (unsigned short*)((char*)d_ws + 25165824);
  unsigned short* aoT  = (unsigned short*)((char*)d_ws + 25165824);
  unsigned short* xT   = (unsigned short*)((char*)d_ws + 33554432);
  unsigned short* pwf  = (unsigned short*)((char*)d_ws + 33554432);
  float* prep          = (float*)d_out;

  cast_qw<<<25, 256, 0, stream>>>(qw, qwf, dcb, w1, dc1b, rpb, prep);
  cast_xT<<<dim3(64, 4, BB), 256, 0, stream>>>(x, xT);
  qkv_mfma<<<dim3(32, BB), 256, 0, stream>>>(xT, qwf, qb, qkvt);
  cast_pw<<<8, 256, 0, stream>>>(pw, pwf);
  attn_kernel<<<dim3(BB * NHEAD, 32), 512, 0, stream>>>(qkvt, prep, aoT);
  proj_mfma<<<dim3(32, BB), 256, 0, stream>>>(aoT, pwf, pb, (float*)d_out);
}